// Round 6
// baseline (189.046 us; speedup 1.0000x reference)
//
#include <hip/hip_runtime.h>
#include <hip/hip_bf16.h>

// ILA layer (fp32 I/O): key = W@ft, query = W@fk (1x1 conv, shared W),
// sim[p,k] = <query[p], key[neighbor_k(p)]> over 9x9 window (zero-padded keys),
// weight = softmax_k(sim)  (OOB entries participate with sim=0),
// out[c,p] = sum_k weight[k] * ft[c, neighbor_k(p)]  (zero-padded ft).
// n=2, c=128, h=w=64, L=9 (81 neighbors).
// R24 = R23 (76.2 us) phases MERGED into one launch with a device-scope
// global barrier (512 blocks == 2/CU co-resident, __launch_bounds__(256,2)).
// Phase A: project the block's own 2x8 tile; Q -> LDS (Qbuf deleted),
// K + fth -> workspace. Barrier: per-thread __threadfence (release/writeback),
// atomicAdd + agent-scope spin, __threadfence (acquire/invalidate) — the G16
// pattern for cross-XCD visibility. Phase B: R23's verified dot/softmax/
// weighting body, qb now from LDS. Counter zeroed via hipMemsetAsync.

#define Hh 64
#define Ww 64
#define Cc 128
#define Nn 2
#define HW (Hh * Ww)          // 4096
#define CHW (Cc * HW)         // 524288
#define NBLK 512u

typedef _Float16 h8 __attribute__((ext_vector_type(8)));
typedef _Float16 h4 __attribute__((ext_vector_type(4)));
typedef float f4v __attribute__((ext_vector_type(4)));

#ifndef __has_builtin
#define __has_builtin(x) 0
#endif

// LDS transpose-read: lane l receives tile[quad*4+j][l&15] of a contiguous
// row-major [16][16] half tile when per-lane addr = tile_base + 8*lane bytes.
#if __has_builtin(__builtin_amdgcn_ds_read_tr16_b64_v4f16)
#define TR_BUILTIN 1
typedef __fp16 g4 __attribute__((__vector_size__(4 * sizeof(__fp16))));
static __device__ __forceinline__ h4 tr16(const _Float16* p) {
    g4 r = __builtin_amdgcn_ds_read_tr16_b64_v4f16(
        (__attribute__((address_space(3))) g4*)p);
    return __builtin_bit_cast(h4, r);
}
#else
#define TR_BUILTIN 0
static __device__ __forceinline__ h4 tr16(const _Float16* p) {
    h4 r;
    asm volatile("ds_read_b64_tr_b16 %0, %1"
                 : "=v"(r)
                 : "v"((__attribute__((address_space(3))) _Float16*)p));
    return r;
}
#endif

// LDS map (bytes):
//   phase A: Wth [0,34816)  xkh [34816,39168)  xqh [39168,43520)
//   phase B: Ksw [0,40960)  ftl [0,41088) (post-B2)
//   both   : Qlds [43520,47872)   (written phase A, read phase B dots)
//            simb [47872,50464)  redM [50464,50720)  redS [50720,50976)
#define FTL2 2568
__global__ __launch_bounds__(256, 2) void ila_merged(const float* __restrict__ ft,
                                                     const float* __restrict__ fk,
                                                     const float* __restrict__ Wm,
                                                     _Float16* __restrict__ Kbuf,
                                                     _Float16* __restrict__ fth,
                                                     unsigned int* __restrict__ cnt,
                                                     float* __restrict__ out) {
    __shared__ __align__(16) unsigned char smem[50976];
    _Float16* Wth  = (_Float16*)smem;             // [o][i] stride 136
    _Float16* xkh  = (_Float16*)(smem + 34816);   // [px16][136]
    _Float16* xqh  = (_Float16*)(smem + 39168);   // [px16][136]
    _Float16* Ksw  = (_Float16*)smem;
    _Float16* ftl  = (_Float16*)smem;
    _Float16* Qlds = (_Float16*)(smem + 43520);   // [px16][136]
    _Float16* simb = (_Float16*)(smem + 47872);   // [k81][16]
    float*    redM = (float*)(smem + 50464);
    float*    redS = (float*)(smem + 50720);

    const int t  = threadIdx.x;
    const int b  = blockIdx.x;
    const int x0 = (b & 7) << 3;
    const int y0 = ((b >> 3) & 31) << 1;
    const int nn = b >> 8;

    const int lane = t & 63, wv = t >> 6;
    const int quad = lane >> 4, l15 = lane & 15;

    // ================= PHASE A: projection for this block's 2x8 tile =========
#pragma unroll 4
    for (int e = t; e < 4096; e += 256) {             // stage W -> fp16
        const int o = e >> 5, ch = e & 31;
        const float4 v = *(const float4*)&Wm[o * 128 + (ch << 2)];
        h4 hv; hv[0] = (_Float16)v.x; hv[1] = (_Float16)v.y;
               hv[2] = (_Float16)v.z; hv[3] = (_Float16)v.w;
        *(h4*)&Wth[o * 136 + (ch << 2)] = hv;
    }
#pragma unroll
    for (int e = t; e < 512; e += 256) {              // stage 2x8 tile, px-major
        const int c = e >> 2, pc = e & 3;
        const int py = pc >> 1, xs4 = (pc & 1) << 2;
        const int ga = nn * CHW + c * HW + ((y0 + py) << 6) + x0 + xs4;
        const float4 vk = *(const float4*)&ft[ga];
        const float4 vq = *(const float4*)&fk[ga];
        const int px = (py << 3) + xs4;
        xkh[(px    ) * 136 + c] = (_Float16)vk.x;
        xkh[(px + 1) * 136 + c] = (_Float16)vk.y;
        xkh[(px + 2) * 136 + c] = (_Float16)vk.z;
        xkh[(px + 3) * 136 + c] = (_Float16)vk.w;
        xqh[(px    ) * 136 + c] = (_Float16)vq.x;
        xqh[(px + 1) * 136 + c] = (_Float16)vq.y;
        xqh[(px + 2) * 136 + c] = (_Float16)vq.z;
        xqh[(px + 3) * 136 + c] = (_Float16)vq.w;
    }
    __syncthreads();

    {   // fth: coalesced h8 copies (fp16 ft, pixel-major), 1 per thread
        const int px = t >> 4, cq = t & 15;
        const size_t gp = (size_t)((nn << 12) + ((y0 + (px >> 3)) << 6) + x0 + (px & 7)) * 128;
        *(h8*)&fth[gp + (cq << 3)] = *(const h8*)&xkh[px * 136 + (cq << 3)];
    }

    {   // proj MFMA: waves 0-1 -> K (global), waves 2-3 -> Q (LDS)
        const _Float16* xs = (wv >> 1) ? xqh : xkh;
        const int nt0 = (wv & 1) << 2;
        const int abase = l15 * 136 + (quad << 3);
        const h8 a0 = *(const h8*)&xs[abase];
        const h8 a1 = *(const h8*)&xs[abase + 32];
        const h8 a2 = *(const h8*)&xs[abase + 64];
        const h8 a3 = *(const h8*)&xs[abase + 96];
#pragma unroll
        for (int ni = 0; ni < 4; ++ni) {
            const int nt = nt0 + ni;
            const int bbase = (nt * 16 + l15) * 136 + (quad << 3);
            const h8 b0 = *(const h8*)&Wth[bbase];
            const h8 b1 = *(const h8*)&Wth[bbase + 32];
            const h8 b2 = *(const h8*)&Wth[bbase + 64];
            const h8 b3 = *(const h8*)&Wth[bbase + 96];
            f4v acc = {0.f, 0.f, 0.f, 0.f};
            acc = __builtin_amdgcn_mfma_f32_16x16x32_f16(a0, b0, acc, 0, 0, 0);
            acc = __builtin_amdgcn_mfma_f32_16x16x32_f16(a1, b1, acc, 0, 0, 0);
            acc = __builtin_amdgcn_mfma_f32_16x16x32_f16(a2, b2, acc, 0, 0, 0);
            acc = __builtin_amdgcn_mfma_f32_16x16x32_f16(a3, b3, acc, 0, 0, 0);
            const int col = nt * 16 + l15;
            if (wv >> 1) {
#pragma unroll
                for (int r = 0; r < 4; ++r)
                    Qlds[((quad << 2) + r) * 136 + col] = (_Float16)acc[r];
            } else {
#pragma unroll
                for (int r = 0; r < 4; ++r) {
                    const int p = (quad << 2) + r;
                    Kbuf[(size_t)((nn << 12) + ((y0 + (p >> 3)) << 6) + x0 + (p & 7)) * 128 + col] =
                        (_Float16)acc[r];
                }
            }
        }
    }

    // ================= GLOBAL BARRIER (device scope, all 512 blocks resident)
    __threadfence();                      // release: drain + L2 writeback
    __syncthreads();
    if (t == 0) {
        __hip_atomic_fetch_add(cnt, 1u, __ATOMIC_ACQ_REL, __HIP_MEMORY_SCOPE_AGENT);
        while (__hip_atomic_load(cnt, __ATOMIC_ACQUIRE, __HIP_MEMORY_SCOPE_AGENT) < NBLK)
            __builtin_amdgcn_s_sleep(2);
    }
    __syncthreads();
    __threadfence();                      // acquire: invalidate stale L1/L2 lines

    // ================= PHASE B: dots + softmax + weighting (R23 verified body)
    // ---- stage K: zero-padded 10x16 window, h8 copies, XOR-swizzled slots
#pragma unroll
    for (int i = 0; i < 10; ++i) {
        const int e = t + (i << 8);               // 160*16 == 2560 == 10*256
        const int v = e >> 4, ci = e & 15;
        const int gx = x0 + (v & 15) - 4;
        const int gy = y0 + (v >> 4) - 4;
        h8 val = {0, 0, 0, 0, 0, 0, 0, 0};
        if ((unsigned)gx < 64u && (unsigned)gy < 64u)
            val = *(const h8*)&Kbuf[(size_t)((nn << 12) + (gy << 6) + gx) * 128 + (ci << 3)];
        *(h8*)&Ksw[(v << 7) + ((ci ^ (v & 15)) << 3)] = val;
    }
    __syncthreads();   // B1

    // ---- PREFETCH ftl source data into registers: overlaps the whole dot phase
    h8 pf[10];
#pragma unroll
    for (int i = 0; i < 10; ++i) {
        const int e = t + (i << 8);
        const int v = e >> 4, ci = e & 15;
        const int gx = x0 + (v & 15) - 4;
        const int gy = y0 + (v >> 4) - 4;
        h8 val = {0, 0, 0, 0, 0, 0, 0, 0};
        if ((unsigned)gx < 64u && (unsigned)gy < 64u)
            val = *(const h8*)&fth[(size_t)((nn << 12) + (gy << 6) + gx) * 128 + (ci << 3)];
        pf[i] = val;
    }

    // ---- dots via MFMA: per window-row r, S_r[xx][p] = sum_c K[r*16+xx][c]*Q[p][c]
    // Wave wv: rows {wv, wv+4, 8, 9}. p = l15 = 16 real px (py=l15>>3, px=l15&7).
    const int py = l15 >> 3, px = l15 & 7;
    h8 qb[4];
#pragma unroll
    for (int kc = 0; kc < 4; ++kc)
        qb[kc] = *(const h8*)&Qlds[l15 * 136 + (((kc << 2) + quad) << 3)];
    f4v sa = {0.f, 0.f, 0.f, 0.f}, sb = sa, sc = sa, sd = sa;
#pragma unroll
    for (int kc = 0; kc < 4; ++kc) {
        const int ci = (kc << 2) + quad;
        const h8 kA = *(const h8*)&Ksw[((((wv    ) << 4) + l15) << 7) + ((ci ^ l15) << 3)];
        const h8 kB = *(const h8*)&Ksw[((((wv + 4) << 4) + l15) << 7) + ((ci ^ l15) << 3)];
        const h8 kC = *(const h8*)&Ksw[((((8     ) << 4) + l15) << 7) + ((ci ^ l15) << 3)];
        const h8 kD = *(const h8*)&Ksw[((((9     ) << 4) + l15) << 7) + ((ci ^ l15) << 3)];
        sa = __builtin_amdgcn_mfma_f32_16x16x32_f16(kA, qb[kc], sa, 0, 0, 0);
        sb = __builtin_amdgcn_mfma_f32_16x16x32_f16(kB, qb[kc], sb, 0, 0, 0);
        sc = __builtin_amdgcn_mfma_f32_16x16x32_f16(kC, qb[kc], sc, 0, 0, 0);
        sd = __builtin_amdgcn_mfma_f32_16x16x32_f16(kD, qb[kc], sd, 0, 0, 0);
    }

    // ---- in-layout softmax, phase 1: band-masked max. D: row xx=quad*4+reg, col p=l15.
    float m = -3.0e38f;
#pragma unroll
    for (int reg = 0; reg < 4; ++reg) {
        const int dx = (quad << 2) + reg - px;
        if ((unsigned)dx < 9u) {
            if ((unsigned)(wv - py) < 9u) m = fmaxf(m, sa[reg]);  // r=wv
            m = fmaxf(m, sb[reg]);                                // r=wv+4 always valid
            m = fmaxf(m, sc[reg]);                                // r=8 always valid
            if (py) m = fmaxf(m, sd[reg]);                        // r=9 only for py=1
        }
    }
    m = fmaxf(m, __shfl_xor(m, 16));
    m = fmaxf(m, __shfl_xor(m, 32));
    if (quad == 0) redM[(wv << 4) + l15] = m;
    __syncthreads();   // B2: dots' Ksw reads done; redM complete; ftl may overwrite

    // ---- restage ft from PREFETCHED registers into [chunk][r][xx][16c] tiles
#pragma unroll
    for (int i = 0; i < 10; ++i) {
        const int e = t + (i << 8);
        const int v = e >> 4, ci = e & 15;
        *(h8*)&ftl[(ci >> 1) * FTL2 + (v << 4) + ((ci & 1) << 3)] = pf[i];
    }

    // ---- phase 2: exp + write simb (fp16, [k81][p16]) + band-masked sum
    const float mm = fmaxf(fmaxf(redM[l15], redM[16 + l15]),
                           fmaxf(redM[32 + l15], redM[48 + l15]));
    float ssum = 0.f;
#pragma unroll
    for (int reg = 0; reg < 4; ++reg) {
        const int dx = (quad << 2) + reg - px;
        const bool okx = (unsigned)dx < 9u;
        {   // r = wv (unique owner)
            const int ry = wv - py;
            const bool ok = okx && ((unsigned)ry < 9u);
            const float e = ok ? __expf(sa[reg] - mm) : 0.f;
            if (ok) simb[((ry * 9 + dx) << 4) + l15] = (_Float16)e;
            ssum += e;
        }
        {   // r = wv+4 (unique owner, always valid)
            const int ry = wv + 4 - py;
            const float e = okx ? __expf(sb[reg] - mm) : 0.f;
            if (okx) simb[((ry * 9 + dx) << 4) + l15] = (_Float16)e;
            ssum += e;
        }
        {   // r = 8, owner wave 0
            const int ry = 8 - py;
            const bool ok = okx && (wv == 0);
            const float e = ok ? __expf(sc[reg] - mm) : 0.f;
            if (ok) simb[((ry * 9 + dx) << 4) + l15] = (_Float16)e;
            ssum += e;
        }
        {   // r = 9, owner wave 1, valid only for py=1 (ry=8)
            const bool ok = okx && (wv == 1) && (py == 1);
            const float e = ok ? __expf(sd[reg] - mm) : 0.f;
            if (ok) simb[((8 * 9 + dx) << 4) + l15] = (_Float16)e;
            ssum += e;
        }
    }
    ssum += __shfl_xor(ssum, 16);
    ssum += __shfl_xor(ssum, 32);
    if (quad == 0) redS[(wv << 4) + l15] = ssum;
    __syncthreads();   // B3: ftl + simb + redS complete

    // ---- B-fragments for the weighting MFMAs: 20 tr reads (chunks wv, wv+4)
    const _Float16* ftc0 = ftl + wv * FTL2;
    const _Float16* ftc1 = ftl + (wv + 4) * FTL2;
    h4 bfr[20];
#pragma unroll
    for (int r = 0; r < 10; ++r) {
        bfr[r]      = tr16(ftc0 + (r << 8) + (lane << 2));
        bfr[10 + r] = tr16(ftc1 + (r << 8) + (lane << 2));
    }

#if !TR_BUILTIN
    asm volatile("s_waitcnt lgkmcnt(0)");   // rule-#18 fence for asm-path bfr
    __builtin_amdgcn_sched_barrier(0);
#endif

    // ---- weighting via MFMA: per window-row r, D[p][c] += A[p][xx] * B_r[xx][c]
    f4v aw0 = {0.f, 0.f, 0.f, 0.f}, aw1 = aw0;
#pragma unroll
    for (int r = 0; r < 10; ++r) {
        const int ry = r - py;
        const bool okr = (unsigned)ry < 9u;
        h4 afr;
#pragma unroll
        for (int j = 0; j < 4; ++j) {
            const int dx = (quad << 2) + j - px;
            const bool ok = okr && ((unsigned)dx < 9u);
            afr[j] = ok ? simb[(((ry * 9 + dx) << 4)) + l15] : (_Float16)0.f;
        }
        aw0 = __builtin_amdgcn_mfma_f32_16x16x16f16(afr, bfr[r],      aw0, 0, 0, 0);
        aw1 = __builtin_amdgcn_mfma_f32_16x16x16f16(afr, bfr[10 + r], aw1, 0, 0, 0);
    }

    // D layout: row = p = quad*4+reg (16 real px), col = c-in-chunk = l15.
    {
        const int p0q = quad << 2;
        const float iv0 = 1.f / (redS[p0q    ] + redS[16 + p0q    ] + redS[32 + p0q    ] + redS[48 + p0q    ]);
        const float iv1 = 1.f / (redS[p0q + 1] + redS[16 + p0q + 1] + redS[32 + p0q + 1] + redS[48 + p0q + 1]);
        const float iv2 = 1.f / (redS[p0q + 2] + redS[16 + p0q + 2] + redS[32 + p0q + 2] + redS[48 + p0q + 2]);
        const float iv3 = 1.f / (redS[p0q + 3] + redS[16 + p0q + 3] + redS[32 + p0q + 3] + redS[48 + p0q + 3]);
        const int yo = y0 + (p0q >> 3);
        const int xb = (yo << 6) + x0 + (p0q & 7);
        const int c0 = (wv << 4) + l15;
        const int c1 = ((wv + 4) << 4) + l15;
        const size_t ob0 = ((size_t)((nn << 7) + c0) << 12) + xb;
        const size_t ob1 = ((size_t)((nn << 7) + c1) << 12) + xb;
        float4 o0, o1;
        o0.x = aw0[0] * iv0; o0.y = aw0[1] * iv1; o0.z = aw0[2] * iv2; o0.w = aw0[3] * iv3;
        o1.x = aw1[0] * iv0; o1.y = aw1[1] * iv1; o1.z = aw1[2] * iv2; o1.w = aw1[3] * iv3;
        *(float4*)&out[ob0] = o0;
        *(float4*)&out[ob1] = o1;
    }
}

extern "C" void kernel_launch(void* const* d_in, const int* in_sizes, int n_in,
                              void* d_out, int out_size, void* d_ws, size_t ws_size,
                              hipStream_t stream) {
    const float* ft = (const float*)d_in[0];
    const float* fk = (const float*)d_in[1];
    const float* Wm = (const float*)d_in[2];
    float* out = (float*)d_out;

    _Float16* Kbuf = (_Float16*)d_ws;                         // [8192][128] fp16
    _Float16* fth  = (_Float16*)d_ws + 1048576;               // [8192][128] fp16
    unsigned int* cnt = (unsigned int*)((char*)d_ws + (4u << 20));

    hipMemsetAsync(cnt, 0, 128, stream);
    ila_merged<<<512, 256, 0, stream>>>(ft, fk, Wm, Kbuf, fth, cnt, out);
}

// Round 7
// 124.166 us; speedup vs baseline: 1.5225x; 1.5225x over previous
//
#include <hip/hip_runtime.h>
#include <hip/hip_bf16.h>

// ILA layer (fp32 I/O): key = W@ft, query = W@fk (1x1 conv, shared W),
// sim[p,k] = <query[p], key[neighbor_k(p)]> over 9x9 window (zero-padded keys),
// weight = softmax_k(sim)  (OOB entries participate with sim=0),
// out[c,p] = sum_k weight[k] * ft[c, neighbor_k(p)]  (zero-padded ft).
// n=2, c=128, h=w=64, L=9 (81 neighbors).
// R25 = R24 (merged, CORRECT but 135us kernel) with the barrier protocol fixed:
// R24 spun on an ACQUIRE agent load (buffer_inv per poll x 512 blocks = TCC
// invalidation storm) and issued per-thread threadfences (2048 wbl2). Now:
// syncthreads (drains vmcnt) -> t0: ONE release fence (single wbl2/block) +
// RELAXED fetch_add + RELAXED spin with s_sleep(32) -> syncthreads -> ONE
// acquire fence after exit. Phases A/B byte-identical to R24 (passed).

#define Hh 64
#define Ww 64
#define Cc 128
#define Nn 2
#define HW (Hh * Ww)          // 4096
#define CHW (Cc * HW)         // 524288
#define NBLK 512u

typedef _Float16 h8 __attribute__((ext_vector_type(8)));
typedef _Float16 h4 __attribute__((ext_vector_type(4)));
typedef float f4v __attribute__((ext_vector_type(4)));

#ifndef __has_builtin
#define __has_builtin(x) 0
#endif

// LDS transpose-read: lane l receives tile[quad*4+j][l&15] of a contiguous
// row-major [16][16] half tile when per-lane addr = tile_base + 8*lane bytes.
#if __has_builtin(__builtin_amdgcn_ds_read_tr16_b64_v4f16)
#define TR_BUILTIN 1
typedef __fp16 g4 __attribute__((__vector_size__(4 * sizeof(__fp16))));
static __device__ __forceinline__ h4 tr16(const _Float16* p) {
    g4 r = __builtin_amdgcn_ds_read_tr16_b64_v4f16(
        (__attribute__((address_space(3))) g4*)p);
    return __builtin_bit_cast(h4, r);
}
#else
#define TR_BUILTIN 0
static __device__ __forceinline__ h4 tr16(const _Float16* p) {
    h4 r;
    asm volatile("ds_read_b64_tr_b16 %0, %1"
                 : "=v"(r)
                 : "v"((__attribute__((address_space(3))) _Float16*)p));
    return r;
}
#endif

// LDS map (bytes):
//   phase A: Wth [0,34816)  xkh [34816,39168)  xqh [39168,43520)
//   phase B: Ksw [0,40960)  ftl [0,41088) (post-B2)
//   both   : Qlds [43520,47872)   (written phase A, read phase B dots)
//            simb [47872,50464)  redM [50464,50720)  redS [50720,50976)
#define FTL2 2568
__global__ __launch_bounds__(256, 2) void ila_merged(const float* __restrict__ ft,
                                                     const float* __restrict__ fk,
                                                     const float* __restrict__ Wm,
                                                     _Float16* __restrict__ Kbuf,
                                                     _Float16* __restrict__ fth,
                                                     unsigned int* __restrict__ cnt,
                                                     float* __restrict__ out) {
    __shared__ __align__(16) unsigned char smem[50976];
    _Float16* Wth  = (_Float16*)smem;             // [o][i] stride 136
    _Float16* xkh  = (_Float16*)(smem + 34816);   // [px16][136]
    _Float16* xqh  = (_Float16*)(smem + 39168);   // [px16][136]
    _Float16* Ksw  = (_Float16*)smem;
    _Float16* ftl  = (_Float16*)smem;
    _Float16* Qlds = (_Float16*)(smem + 43520);   // [px16][136]
    _Float16* simb = (_Float16*)(smem + 47872);   // [k81][16]
    float*    redM = (float*)(smem + 50464);
    float*    redS = (float*)(smem + 50720);

    const int t  = threadIdx.x;
    const int b  = blockIdx.x;
    const int x0 = (b & 7) << 3;
    const int y0 = ((b >> 3) & 31) << 1;
    const int nn = b >> 8;

    const int lane = t & 63, wv = t >> 6;
    const int quad = lane >> 4, l15 = lane & 15;

    // ================= PHASE A: projection for this block's 2x8 tile =========
#pragma unroll 4
    for (int e = t; e < 4096; e += 256) {             // stage W -> fp16
        const int o = e >> 5, ch = e & 31;
        const float4 v = *(const float4*)&Wm[o * 128 + (ch << 2)];
        h4 hv; hv[0] = (_Float16)v.x; hv[1] = (_Float16)v.y;
               hv[2] = (_Float16)v.z; hv[3] = (_Float16)v.w;
        *(h4*)&Wth[o * 136 + (ch << 2)] = hv;
    }
#pragma unroll
    for (int e = t; e < 512; e += 256) {              // stage 2x8 tile, px-major
        const int c = e >> 2, pc = e & 3;
        const int py = pc >> 1, xs4 = (pc & 1) << 2;
        const int ga = nn * CHW + c * HW + ((y0 + py) << 6) + x0 + xs4;
        const float4 vk = *(const float4*)&ft[ga];
        const float4 vq = *(const float4*)&fk[ga];
        const int px = (py << 3) + xs4;
        xkh[(px    ) * 136 + c] = (_Float16)vk.x;
        xkh[(px + 1) * 136 + c] = (_Float16)vk.y;
        xkh[(px + 2) * 136 + c] = (_Float16)vk.z;
        xkh[(px + 3) * 136 + c] = (_Float16)vk.w;
        xqh[(px    ) * 136 + c] = (_Float16)vq.x;
        xqh[(px + 1) * 136 + c] = (_Float16)vq.y;
        xqh[(px + 2) * 136 + c] = (_Float16)vq.z;
        xqh[(px + 3) * 136 + c] = (_Float16)vq.w;
    }
    __syncthreads();

    {   // fth: coalesced h8 copies (fp16 ft, pixel-major), 1 per thread
        const int px = t >> 4, cq = t & 15;
        const size_t gp = (size_t)((nn << 12) + ((y0 + (px >> 3)) << 6) + x0 + (px & 7)) * 128;
        *(h8*)&fth[gp + (cq << 3)] = *(const h8*)&xkh[px * 136 + (cq << 3)];
    }

    {   // proj MFMA: waves 0-1 -> K (global), waves 2-3 -> Q (LDS)
        const _Float16* xs = (wv >> 1) ? xqh : xkh;
        const int nt0 = (wv & 1) << 2;
        const int abase = l15 * 136 + (quad << 3);
        const h8 a0 = *(const h8*)&xs[abase];
        const h8 a1 = *(const h8*)&xs[abase + 32];
        const h8 a2 = *(const h8*)&xs[abase + 64];
        const h8 a3 = *(const h8*)&xs[abase + 96];
#pragma unroll
        for (int ni = 0; ni < 4; ++ni) {
            const int nt = nt0 + ni;
            const int bbase = (nt * 16 + l15) * 136 + (quad << 3);
            const h8 b0 = *(const h8*)&Wth[bbase];
            const h8 b1 = *(const h8*)&Wth[bbase + 32];
            const h8 b2 = *(const h8*)&Wth[bbase + 64];
            const h8 b3 = *(const h8*)&Wth[bbase + 96];
            f4v acc = {0.f, 0.f, 0.f, 0.f};
            acc = __builtin_amdgcn_mfma_f32_16x16x32_f16(a0, b0, acc, 0, 0, 0);
            acc = __builtin_amdgcn_mfma_f32_16x16x32_f16(a1, b1, acc, 0, 0, 0);
            acc = __builtin_amdgcn_mfma_f32_16x16x32_f16(a2, b2, acc, 0, 0, 0);
            acc = __builtin_amdgcn_mfma_f32_16x16x32_f16(a3, b3, acc, 0, 0, 0);
            const int col = nt * 16 + l15;
            if (wv >> 1) {
#pragma unroll
                for (int r = 0; r < 4; ++r)
                    Qlds[((quad << 2) + r) * 136 + col] = (_Float16)acc[r];
            } else {
#pragma unroll
                for (int r = 0; r < 4; ++r) {
                    const int p = (quad << 2) + r;
                    Kbuf[(size_t)((nn << 12) + ((y0 + (p >> 3)) << 6) + x0 + (p & 7)) * 128 + col] =
                        (_Float16)acc[r];
                }
            }
        }
    }

    // ================= GLOBAL BARRIER (device scope, all 512 blocks resident)
    // syncthreads drains each wave's vmcnt (stores are in L2 after this).
    __syncthreads();
    if (t == 0) {
        __builtin_amdgcn_fence(__ATOMIC_RELEASE, "agent");   // one wbl2 per block
        __hip_atomic_fetch_add(cnt, 1u, __ATOMIC_RELAXED, __HIP_MEMORY_SCOPE_AGENT);
        while (__hip_atomic_load(cnt, __ATOMIC_RELAXED, __HIP_MEMORY_SCOPE_AGENT) < NBLK)
            __builtin_amdgcn_s_sleep(32);                    // relaxed poll: no inv
    }
    __syncthreads();
    __builtin_amdgcn_fence(__ATOMIC_ACQUIRE, "agent");       // one invalidate, post-spin

    // ================= PHASE B: dots + softmax + weighting (R23 verified body)
    // ---- stage K: zero-padded 10x16 window, h8 copies, XOR-swizzled slots
#pragma unroll
    for (int i = 0; i < 10; ++i) {
        const int e = t + (i << 8);               // 160*16 == 2560 == 10*256
        const int v = e >> 4, ci = e & 15;
        const int gx = x0 + (v & 15) - 4;
        const int gy = y0 + (v >> 4) - 4;
        h8 val = {0, 0, 0, 0, 0, 0, 0, 0};
        if ((unsigned)gx < 64u && (unsigned)gy < 64u)
            val = *(const h8*)&Kbuf[(size_t)((nn << 12) + (gy << 6) + gx) * 128 + (ci << 3)];
        *(h8*)&Ksw[(v << 7) + ((ci ^ (v & 15)) << 3)] = val;
    }
    __syncthreads();   // B1

    // ---- PREFETCH ftl source data into registers: overlaps the whole dot phase
    h8 pf[10];
#pragma unroll
    for (int i = 0; i < 10; ++i) {
        const int e = t + (i << 8);
        const int v = e >> 4, ci = e & 15;
        const int gx = x0 + (v & 15) - 4;
        const int gy = y0 + (v >> 4) - 4;
        h8 val = {0, 0, 0, 0, 0, 0, 0, 0};
        if ((unsigned)gx < 64u && (unsigned)gy < 64u)
            val = *(const h8*)&fth[(size_t)((nn << 12) + (gy << 6) + gx) * 128 + (ci << 3)];
        pf[i] = val;
    }

    // ---- dots via MFMA: per window-row r, S_r[xx][p] = sum_c K[r*16+xx][c]*Q[p][c]
    // Wave wv: rows {wv, wv+4, 8, 9}. p = l15 = 16 real px (py=l15>>3, px=l15&7).
    const int py = l15 >> 3, px = l15 & 7;
    h8 qb[4];
#pragma unroll
    for (int kc = 0; kc < 4; ++kc)
        qb[kc] = *(const h8*)&Qlds[l15 * 136 + (((kc << 2) + quad) << 3)];
    f4v sa = {0.f, 0.f, 0.f, 0.f}, sb = sa, sc = sa, sd = sa;
#pragma unroll
    for (int kc = 0; kc < 4; ++kc) {
        const int ci = (kc << 2) + quad;
        const h8 kA = *(const h8*)&Ksw[((((wv    ) << 4) + l15) << 7) + ((ci ^ l15) << 3)];
        const h8 kB = *(const h8*)&Ksw[((((wv + 4) << 4) + l15) << 7) + ((ci ^ l15) << 3)];
        const h8 kC = *(const h8*)&Ksw[((((8     ) << 4) + l15) << 7) + ((ci ^ l15) << 3)];
        const h8 kD = *(const h8*)&Ksw[((((9     ) << 4) + l15) << 7) + ((ci ^ l15) << 3)];
        sa = __builtin_amdgcn_mfma_f32_16x16x32_f16(kA, qb[kc], sa, 0, 0, 0);
        sb = __builtin_amdgcn_mfma_f32_16x16x32_f16(kB, qb[kc], sb, 0, 0, 0);
        sc = __builtin_amdgcn_mfma_f32_16x16x32_f16(kC, qb[kc], sc, 0, 0, 0);
        sd = __builtin_amdgcn_mfma_f32_16x16x32_f16(kD, qb[kc], sd, 0, 0, 0);
    }

    // ---- in-layout softmax, phase 1: band-masked max. D: row xx=quad*4+reg, col p=l15.
    float m = -3.0e38f;
#pragma unroll
    for (int reg = 0; reg < 4; ++reg) {
        const int dx = (quad << 2) + reg - px;
        if ((unsigned)dx < 9u) {
            if ((unsigned)(wv - py) < 9u) m = fmaxf(m, sa[reg]);  // r=wv
            m = fmaxf(m, sb[reg]);                                // r=wv+4 always valid
            m = fmaxf(m, sc[reg]);                                // r=8 always valid
            if (py) m = fmaxf(m, sd[reg]);                        // r=9 only for py=1
        }
    }
    m = fmaxf(m, __shfl_xor(m, 16));
    m = fmaxf(m, __shfl_xor(m, 32));
    if (quad == 0) redM[(wv << 4) + l15] = m;
    __syncthreads();   // B2: dots' Ksw reads done; redM complete; ftl may overwrite

    // ---- restage ft from PREFETCHED registers into [chunk][r][xx][16c] tiles
#pragma unroll
    for (int i = 0; i < 10; ++i) {
        const int e = t + (i << 8);
        const int v = e >> 4, ci = e & 15;
        *(h8*)&ftl[(ci >> 1) * FTL2 + (v << 4) + ((ci & 1) << 3)] = pf[i];
    }

    // ---- phase 2: exp + write simb (fp16, [k81][p16]) + band-masked sum
    const float mm = fmaxf(fmaxf(redM[l15], redM[16 + l15]),
                           fmaxf(redM[32 + l15], redM[48 + l15]));
    float ssum = 0.f;
#pragma unroll
    for (int reg = 0; reg < 4; ++reg) {
        const int dx = (quad << 2) + reg - px;
        const bool okx = (unsigned)dx < 9u;
        {   // r = wv (unique owner)
            const int ry = wv - py;
            const bool ok = okx && ((unsigned)ry < 9u);
            const float e = ok ? __expf(sa[reg] - mm) : 0.f;
            if (ok) simb[((ry * 9 + dx) << 4) + l15] = (_Float16)e;
            ssum += e;
        }
        {   // r = wv+4 (unique owner, always valid)
            const int ry = wv + 4 - py;
            const float e = okx ? __expf(sb[reg] - mm) : 0.f;
            if (okx) simb[((ry * 9 + dx) << 4) + l15] = (_Float16)e;
            ssum += e;
        }
        {   // r = 8, owner wave 0
            const int ry = 8 - py;
            const bool ok = okx && (wv == 0);
            const float e = ok ? __expf(sc[reg] - mm) : 0.f;
            if (ok) simb[((ry * 9 + dx) << 4) + l15] = (_Float16)e;
            ssum += e;
        }
        {   // r = 9, owner wave 1, valid only for py=1 (ry=8)
            const bool ok = okx && (wv == 1) && (py == 1);
            const float e = ok ? __expf(sd[reg] - mm) : 0.f;
            if (ok) simb[((8 * 9 + dx) << 4) + l15] = (_Float16)e;
            ssum += e;
        }
    }
    ssum += __shfl_xor(ssum, 16);
    ssum += __shfl_xor(ssum, 32);
    if (quad == 0) redS[(wv << 4) + l15] = ssum;
    __syncthreads();   // B3: ftl + simb + redS complete

    // ---- B-fragments for the weighting MFMAs: 20 tr reads (chunks wv, wv+4)
    const _Float16* ftc0 = ftl + wv * FTL2;
    const _Float16* ftc1 = ftl + (wv + 4) * FTL2;
    h4 bfr[20];
#pragma unroll
    for (int r = 0; r < 10; ++r) {
        bfr[r]      = tr16(ftc0 + (r << 8) + (lane << 2));
        bfr[10 + r] = tr16(ftc1 + (r << 8) + (lane << 2));
    }

#if !TR_BUILTIN
    asm volatile("s_waitcnt lgkmcnt(0)");   // rule-#18 fence for asm-path bfr
    __builtin_amdgcn_sched_barrier(0);
#endif

    // ---- weighting via MFMA: per window-row r, D[p][c] += A[p][xx] * B_r[xx][c]
    f4v aw0 = {0.f, 0.f, 0.f, 0.f}, aw1 = aw0;
#pragma unroll
    for (int r = 0; r < 10; ++r) {
        const int ry = r - py;
        const bool okr = (unsigned)ry < 9u;
        h4 afr;
#pragma unroll
        for (int j = 0; j < 4; ++j) {
            const int dx = (quad << 2) + j - px;
            const bool ok = okr && ((unsigned)dx < 9u);
            afr[j] = ok ? simb[(((ry * 9 + dx) << 4)) + l15] : (_Float16)0.f;
        }
        aw0 = __builtin_amdgcn_mfma_f32_16x16x16f16(afr, bfr[r],      aw0, 0, 0, 0);
        aw1 = __builtin_amdgcn_mfma_f32_16x16x16f16(afr, bfr[10 + r], aw1, 0, 0, 0);
    }

    // D layout: row = p = quad*4+reg (16 real px), col = c-in-chunk = l15.
    {
        const int p0q = quad << 2;
        const float iv0 = 1.f / (redS[p0q    ] + redS[16 + p0q    ] + redS[32 + p0q    ] + redS[48 + p0q    ]);
        const float iv1 = 1.f / (redS[p0q + 1] + redS[16 + p0q + 1] + redS[32 + p0q + 1] + redS[48 + p0q + 1]);
        const float iv2 = 1.f / (redS[p0q + 2] + redS[16 + p0q + 2] + redS[32 + p0q + 2] + redS[48 + p0q + 2]);
        const float iv3 = 1.f / (redS[p0q + 3] + redS[16 + p0q + 3] + redS[32 + p0q + 3] + redS[48 + p0q + 3]);
        const int yo = y0 + (p0q >> 3);
        const int xb = (yo << 6) + x0 + (p0q & 7);
        const int c0 = (wv << 4) + l15;
        const int c1 = ((wv + 4) << 4) + l15;
        const size_t ob0 = ((size_t)((nn << 7) + c0) << 12) + xb;
        const size_t ob1 = ((size_t)((nn << 7) + c1) << 12) + xb;
        float4 o0, o1;
        o0.x = aw0[0] * iv0; o0.y = aw0[1] * iv1; o0.z = aw0[2] * iv2; o0.w = aw0[3] * iv3;
        o1.x = aw1[0] * iv0; o1.y = aw1[1] * iv1; o1.z = aw1[2] * iv2; o1.w = aw1[3] * iv3;
        *(float4*)&out[ob0] = o0;
        *(float4*)&out[ob1] = o1;
    }
}

extern "C" void kernel_launch(void* const* d_in, const int* in_sizes, int n_in,
                              void* d_out, int out_size, void* d_ws, size_t ws_size,
                              hipStream_t stream) {
    const float* ft = (const float*)d_in[0];
    const float* fk = (const float*)d_in[1];
    const float* Wm = (const float*)d_in[2];
    float* out = (float*)d_out;

    _Float16* Kbuf = (_Float16*)d_ws;                         // [8192][128] fp16
    _Float16* fth  = (_Float16*)d_ws + 1048576;               // [8192][128] fp16
    unsigned int* cnt = (unsigned int*)((char*)d_ws + (4u << 20));

    hipMemsetAsync(cnt, 0, 128, stream);
    ila_merged<<<512, 256, 0, stream>>>(ft, fk, Wm, Kbuf, fth, cnt, out);
}

// Round 8
// 106.692 us; speedup vs baseline: 1.7719x; 1.1638x over previous
//
#include <hip/hip_runtime.h>
#include <hip/hip_bf16.h>

// ILA layer (fp32 I/O): key = W@ft, query = W@fk (1x1 conv, shared W),
// sim[p,k] = <query[p], key[neighbor_k(p)]> over 9x9 window (zero-padded keys),
// weight = softmax_k(sim)  (OOB entries participate with sim=0),
// out[c,p] = sum_k weight[k] * ft[c, neighbor_k(p)]  (zero-padded ft).
// n=2, c=128, h=w=64, L=9 (81 neighbors).
// R26 = R25 (merged, 69us kernel) with ALL cache-maintenance ops removed:
// R25 still paid 512 buffer_wbl2 (release) + 512 buffer_inv (acquire) tag-walks.
// Now Kbuf/fth are written with RELAXED AGENT-scope atomic u64 stores (scope
// drives sc-bits -> write-through to LLC; no wbl2). Readers never touched these
// addresses pre-barrier and the preceding dispatch-end release cleaned L2s ->
// plain loads clean-miss to LLC; no acquire inv. Barrier = syncthreads ->
// t0 relaxed fetch_add + relaxed spin (s_sleep 8) -> syncthreads. Zero fences.
// K path: acc -> Klds (h4) -> coalesced u64 atomic copy (with fth's).

#define Hh 64
#define Ww 64
#define Cc 128
#define Nn 2
#define HW (Hh * Ww)          // 4096
#define CHW (Cc * HW)         // 524288
#define NBLK 512u

typedef _Float16 h8 __attribute__((ext_vector_type(8)));
typedef _Float16 h4 __attribute__((ext_vector_type(4)));
typedef float f4v __attribute__((ext_vector_type(4)));
typedef unsigned long long u64;
typedef u64 u64x2 __attribute__((ext_vector_type(2)));

#ifndef __has_builtin
#define __has_builtin(x) 0
#endif

// LDS transpose-read: lane l receives tile[quad*4+j][l&15] of a contiguous
// row-major [16][16] half tile when per-lane addr = tile_base + 8*lane bytes.
#if __has_builtin(__builtin_amdgcn_ds_read_tr16_b64_v4f16)
#define TR_BUILTIN 1
typedef __fp16 g4 __attribute__((__vector_size__(4 * sizeof(__fp16))));
static __device__ __forceinline__ h4 tr16(const _Float16* p) {
    g4 r = __builtin_amdgcn_ds_read_tr16_b64_v4f16(
        (__attribute__((address_space(3))) g4*)p);
    return __builtin_bit_cast(h4, r);
}
#else
#define TR_BUILTIN 0
static __device__ __forceinline__ h4 tr16(const _Float16* p) {
    h4 r;
    asm volatile("ds_read_b64_tr_b16 %0, %1"
                 : "=v"(r)
                 : "v"((__attribute__((address_space(3))) _Float16*)p));
    return r;
}
#endif

// LDS map (bytes):
//   phase A: Wth [0,34816)  xkh [34816,39168)  xqh [39168,43520)
//            Klds [47872,52224)   (dead after pre-barrier copy-out)
//   phase B: Ksw [0,40960)  ftl [0,41088) (post-B2)
//            simb [47872,50464)  redM [50464,50720)  redS [50720,50976)
//   both   : Qlds [43520,47872)
#define FTL2 2568
__global__ __launch_bounds__(256, 2) void ila_merged(const float* __restrict__ ft,
                                                     const float* __restrict__ fk,
                                                     const float* __restrict__ Wm,
                                                     _Float16* __restrict__ Kbuf,
                                                     _Float16* __restrict__ fth,
                                                     unsigned int* __restrict__ cnt,
                                                     float* __restrict__ out) {
    __shared__ __align__(16) unsigned char smem[52224];
    _Float16* Wth  = (_Float16*)smem;             // [o][i] stride 136
    _Float16* xkh  = (_Float16*)(smem + 34816);   // [px16][136]
    _Float16* xqh  = (_Float16*)(smem + 39168);   // [px16][136]
    _Float16* Ksw  = (_Float16*)smem;
    _Float16* ftl  = (_Float16*)smem;
    _Float16* Qlds = (_Float16*)(smem + 43520);   // [px16][136]
    _Float16* Klds = (_Float16*)(smem + 47872);   // [px16][136] phase A only
    _Float16* simb = (_Float16*)(smem + 47872);   // [k81][16]  phase B only
    float*    redM = (float*)(smem + 50464);
    float*    redS = (float*)(smem + 50720);

    const int t  = threadIdx.x;
    const int b  = blockIdx.x;
    const int x0 = (b & 7) << 3;
    const int y0 = ((b >> 3) & 31) << 1;
    const int nn = b >> 8;

    const int lane = t & 63, wv = t >> 6;
    const int quad = lane >> 4, l15 = lane & 15;

    // ================= PHASE A: projection for this block's 2x8 tile =========
#pragma unroll 4
    for (int e = t; e < 4096; e += 256) {             // stage W -> fp16
        const int o = e >> 5, ch = e & 31;
        const float4 v = *(const float4*)&Wm[o * 128 + (ch << 2)];
        h4 hv; hv[0] = (_Float16)v.x; hv[1] = (_Float16)v.y;
               hv[2] = (_Float16)v.z; hv[3] = (_Float16)v.w;
        *(h4*)&Wth[o * 136 + (ch << 2)] = hv;
    }
#pragma unroll
    for (int e = t; e < 512; e += 256) {              // stage 2x8 tile, px-major
        const int c = e >> 2, pc = e & 3;
        const int py = pc >> 1, xs4 = (pc & 1) << 2;
        const int ga = nn * CHW + c * HW + ((y0 + py) << 6) + x0 + xs4;
        const float4 vk = *(const float4*)&ft[ga];
        const float4 vq = *(const float4*)&fk[ga];
        const int px = (py << 3) + xs4;
        xkh[(px    ) * 136 + c] = (_Float16)vk.x;
        xkh[(px + 1) * 136 + c] = (_Float16)vk.y;
        xkh[(px + 2) * 136 + c] = (_Float16)vk.z;
        xkh[(px + 3) * 136 + c] = (_Float16)vk.w;
        xqh[(px    ) * 136 + c] = (_Float16)vq.x;
        xqh[(px + 1) * 136 + c] = (_Float16)vq.y;
        xqh[(px + 2) * 136 + c] = (_Float16)vq.z;
        xqh[(px + 3) * 136 + c] = (_Float16)vq.w;
    }
    __syncthreads();

    {   // proj MFMA: waves 0-1 -> Klds, waves 2-3 -> Qlds
        const _Float16* xs = (wv >> 1) ? xqh : xkh;
        _Float16* dl = (wv >> 1) ? Qlds : Klds;
        const int nt0 = (wv & 1) << 2;
        const int abase = l15 * 136 + (quad << 3);
        const h8 a0 = *(const h8*)&xs[abase];
        const h8 a1 = *(const h8*)&xs[abase + 32];
        const h8 a2 = *(const h8*)&xs[abase + 64];
        const h8 a3 = *(const h8*)&xs[abase + 96];
#pragma unroll
        for (int ni = 0; ni < 4; ++ni) {
            const int nt = nt0 + ni;
            const int bbase = (nt * 16 + l15) * 136 + (quad << 3);
            const h8 b0 = *(const h8*)&Wth[bbase];
            const h8 b1 = *(const h8*)&Wth[bbase + 32];
            const h8 b2 = *(const h8*)&Wth[bbase + 64];
            const h8 b3 = *(const h8*)&Wth[bbase + 96];
            f4v acc = {0.f, 0.f, 0.f, 0.f};
            acc = __builtin_amdgcn_mfma_f32_16x16x32_f16(a0, b0, acc, 0, 0, 0);
            acc = __builtin_amdgcn_mfma_f32_16x16x32_f16(a1, b1, acc, 0, 0, 0);
            acc = __builtin_amdgcn_mfma_f32_16x16x32_f16(a2, b2, acc, 0, 0, 0);
            acc = __builtin_amdgcn_mfma_f32_16x16x32_f16(a3, b3, acc, 0, 0, 0);
            const int col = nt * 16 + l15;
#pragma unroll
            for (int r = 0; r < 4; ++r)
                dl[((quad << 2) + r) * 136 + col] = (_Float16)acc[r];
        }
    }
    __syncthreads();   // Klds/Qlds complete

    {   // copy-out K + fth via RELAXED AGENT atomic u64 stores (sc -> LLC)
        const int px = t >> 4, cq = t & 15;
        const size_t gp = (size_t)((nn << 12) + ((y0 + (px >> 3)) << 6) + x0 + (px & 7)) * 128
                          + (cq << 3);
        const u64x2 kk = __builtin_bit_cast(u64x2, *(const h8*)&Klds[px * 136 + (cq << 3)]);
        const u64x2 ff = __builtin_bit_cast(u64x2, *(const h8*)&xkh[px * 136 + (cq << 3)]);
        u64* kd = (u64*)&Kbuf[gp];
        u64* fd = (u64*)&fth[gp];
        __hip_atomic_store(kd,     kk[0], __ATOMIC_RELAXED, __HIP_MEMORY_SCOPE_AGENT);
        __hip_atomic_store(kd + 1, kk[1], __ATOMIC_RELAXED, __HIP_MEMORY_SCOPE_AGENT);
        __hip_atomic_store(fd,     ff[0], __ATOMIC_RELAXED, __HIP_MEMORY_SCOPE_AGENT);
        __hip_atomic_store(fd + 1, ff[1], __ATOMIC_RELAXED, __HIP_MEMORY_SCOPE_AGENT);
    }

    // ================= GLOBAL BARRIER (device scope, all 512 blocks resident)
    // syncthreads drains vmcnt (atomic stores are at the LLC after this).
    __syncthreads();
    if (t == 0) {
        __hip_atomic_fetch_add(cnt, 1u, __ATOMIC_RELAXED, __HIP_MEMORY_SCOPE_AGENT);
        while (__hip_atomic_load(cnt, __ATOMIC_RELAXED, __HIP_MEMORY_SCOPE_AGENT) < NBLK)
            __builtin_amdgcn_s_sleep(8);
    }
    __syncthreads();

    // ================= PHASE B: dots + softmax + weighting (R23 verified body)
    // ---- stage K: zero-padded 10x16 window, h8 copies, XOR-swizzled slots
#pragma unroll
    for (int i = 0; i < 10; ++i) {
        const int e = t + (i << 8);               // 160*16 == 2560 == 10*256
        const int v = e >> 4, ci = e & 15;
        const int gx = x0 + (v & 15) - 4;
        const int gy = y0 + (v >> 4) - 4;
        h8 val = {0, 0, 0, 0, 0, 0, 0, 0};
        if ((unsigned)gx < 64u && (unsigned)gy < 64u)
            val = *(const h8*)&Kbuf[(size_t)((nn << 12) + (gy << 6) + gx) * 128 + (ci << 3)];
        *(h8*)&Ksw[(v << 7) + ((ci ^ (v & 15)) << 3)] = val;
    }
    __syncthreads();   // B1

    // ---- PREFETCH ftl source data into registers: overlaps the whole dot phase
    h8 pf[10];
#pragma unroll
    for (int i = 0; i < 10; ++i) {
        const int e = t + (i << 8);
        const int v = e >> 4, ci = e & 15;
        const int gx = x0 + (v & 15) - 4;
        const int gy = y0 + (v >> 4) - 4;
        h8 val = {0, 0, 0, 0, 0, 0, 0, 0};
        if ((unsigned)gx < 64u && (unsigned)gy < 64u)
            val = *(const h8*)&fth[(size_t)((nn << 12) + (gy << 6) + gx) * 128 + (ci << 3)];
        pf[i] = val;
    }

    // ---- dots via MFMA: per window-row r, S_r[xx][p] = sum_c K[r*16+xx][c]*Q[p][c]
    // Wave wv: rows {wv, wv+4, 8, 9}. p = l15 = 16 real px (py=l15>>3, px=l15&7).
    const int py = l15 >> 3, px = l15 & 7;
    h8 qb[4];
#pragma unroll
    for (int kc = 0; kc < 4; ++kc)
        qb[kc] = *(const h8*)&Qlds[l15 * 136 + (((kc << 2) + quad) << 3)];
    f4v sa = {0.f, 0.f, 0.f, 0.f}, sb = sa, sc = sa, sd = sa;
#pragma unroll
    for (int kc = 0; kc < 4; ++kc) {
        const int ci = (kc << 2) + quad;
        const h8 kA = *(const h8*)&Ksw[((((wv    ) << 4) + l15) << 7) + ((ci ^ l15) << 3)];
        const h8 kB = *(const h8*)&Ksw[((((wv + 4) << 4) + l15) << 7) + ((ci ^ l15) << 3)];
        const h8 kC = *(const h8*)&Ksw[((((8     ) << 4) + l15) << 7) + ((ci ^ l15) << 3)];
        const h8 kD = *(const h8*)&Ksw[((((9     ) << 4) + l15) << 7) + ((ci ^ l15) << 3)];
        sa = __builtin_amdgcn_mfma_f32_16x16x32_f16(kA, qb[kc], sa, 0, 0, 0);
        sb = __builtin_amdgcn_mfma_f32_16x16x32_f16(kB, qb[kc], sb, 0, 0, 0);
        sc = __builtin_amdgcn_mfma_f32_16x16x32_f16(kC, qb[kc], sc, 0, 0, 0);
        sd = __builtin_amdgcn_mfma_f32_16x16x32_f16(kD, qb[kc], sd, 0, 0, 0);
    }

    // ---- in-layout softmax, phase 1: band-masked max. D: row xx=quad*4+reg, col p=l15.
    float m = -3.0e38f;
#pragma unroll
    for (int reg = 0; reg < 4; ++reg) {
        const int dx = (quad << 2) + reg - px;
        if ((unsigned)dx < 9u) {
            if ((unsigned)(wv - py) < 9u) m = fmaxf(m, sa[reg]);  // r=wv
            m = fmaxf(m, sb[reg]);                                // r=wv+4 always valid
            m = fmaxf(m, sc[reg]);                                // r=8 always valid
            if (py) m = fmaxf(m, sd[reg]);                        // r=9 only for py=1
        }
    }
    m = fmaxf(m, __shfl_xor(m, 16));
    m = fmaxf(m, __shfl_xor(m, 32));
    if (quad == 0) redM[(wv << 4) + l15] = m;
    __syncthreads();   // B2: dots' Ksw reads done; redM complete; ftl may overwrite

    // ---- restage ft from PREFETCHED registers into [chunk][r][xx][16c] tiles
#pragma unroll
    for (int i = 0; i < 10; ++i) {
        const int e = t + (i << 8);
        const int v = e >> 4, ci = e & 15;
        *(h8*)&ftl[(ci >> 1) * FTL2 + (v << 4) + ((ci & 1) << 3)] = pf[i];
    }

    // ---- phase 2: exp + write simb (fp16, [k81][p16]) + band-masked sum
    const float mm = fmaxf(fmaxf(redM[l15], redM[16 + l15]),
                           fmaxf(redM[32 + l15], redM[48 + l15]));
    float ssum = 0.f;
#pragma unroll
    for (int reg = 0; reg < 4; ++reg) {
        const int dx = (quad << 2) + reg - px;
        const bool okx = (unsigned)dx < 9u;
        {   // r = wv (unique owner)
            const int ry = wv - py;
            const bool ok = okx && ((unsigned)ry < 9u);
            const float e = ok ? __expf(sa[reg] - mm) : 0.f;
            if (ok) simb[((ry * 9 + dx) << 4) + l15] = (_Float16)e;
            ssum += e;
        }
        {   // r = wv+4 (unique owner, always valid)
            const int ry = wv + 4 - py;
            const float e = okx ? __expf(sb[reg] - mm) : 0.f;
            if (okx) simb[((ry * 9 + dx) << 4) + l15] = (_Float16)e;
            ssum += e;
        }
        {   // r = 8, owner wave 0
            const int ry = 8 - py;
            const bool ok = okx && (wv == 0);
            const float e = ok ? __expf(sc[reg] - mm) : 0.f;
            if (ok) simb[((ry * 9 + dx) << 4) + l15] = (_Float16)e;
            ssum += e;
        }
        {   // r = 9, owner wave 1, valid only for py=1 (ry=8)
            const bool ok = okx && (wv == 1) && (py == 1);
            const float e = ok ? __expf(sd[reg] - mm) : 0.f;
            if (ok) simb[((8 * 9 + dx) << 4) + l15] = (_Float16)e;
            ssum += e;
        }
    }
    ssum += __shfl_xor(ssum, 16);
    ssum += __shfl_xor(ssum, 32);
    if (quad == 0) redS[(wv << 4) + l15] = ssum;
    __syncthreads();   // B3: ftl + simb + redS complete

    // ---- B-fragments for the weighting MFMAs: 20 tr reads (chunks wv, wv+4)
    const _Float16* ftc0 = ftl + wv * FTL2;
    const _Float16* ftc1 = ftl + (wv + 4) * FTL2;
    h4 bfr[20];
#pragma unroll
    for (int r = 0; r < 10; ++r) {
        bfr[r]      = tr16(ftc0 + (r << 8) + (lane << 2));
        bfr[10 + r] = tr16(ftc1 + (r << 8) + (lane << 2));
    }

#if !TR_BUILTIN
    asm volatile("s_waitcnt lgkmcnt(0)");   // rule-#18 fence for asm-path bfr
    __builtin_amdgcn_sched_barrier(0);
#endif

    // ---- weighting via MFMA: per window-row r, D[p][c] += A[p][xx] * B_r[xx][c]
    f4v aw0 = {0.f, 0.f, 0.f, 0.f}, aw1 = aw0;
#pragma unroll
    for (int r = 0; r < 10; ++r) {
        const int ry = r - py;
        const bool okr = (unsigned)ry < 9u;
        h4 afr;
#pragma unroll
        for (int j = 0; j < 4; ++j) {
            const int dx = (quad << 2) + j - px;
            const bool ok = okr && ((unsigned)dx < 9u);
            afr[j] = ok ? simb[(((ry * 9 + dx) << 4)) + l15] : (_Float16)0.f;
        }
        aw0 = __builtin_amdgcn_mfma_f32_16x16x16f16(afr, bfr[r],      aw0, 0, 0, 0);
        aw1 = __builtin_amdgcn_mfma_f32_16x16x16f16(afr, bfr[10 + r], aw1, 0, 0, 0);
    }

    // D layout: row = p = quad*4+reg (16 real px), col = c-in-chunk = l15.
    {
        const int p0q = quad << 2;
        const float iv0 = 1.f / (redS[p0q    ] + redS[16 + p0q    ] + redS[32 + p0q    ] + redS[48 + p0q    ]);
        const float iv1 = 1.f / (redS[p0q + 1] + redS[16 + p0q + 1] + redS[32 + p0q + 1] + redS[48 + p0q + 1]);
        const float iv2 = 1.f / (redS[p0q + 2] + redS[16 + p0q + 2] + redS[32 + p0q + 2] + redS[48 + p0q + 2]);
        const float iv3 = 1.f / (redS[p0q + 3] + redS[16 + p0q + 3] + redS[32 + p0q + 3] + redS[48 + p0q + 3]);
        const int yo = y0 + (p0q >> 3);
        const int xb = (yo << 6) + x0 + (p0q & 7);
        const int c0 = (wv << 4) + l15;
        const int c1 = ((wv + 4) << 4) + l15;
        const size_t ob0 = ((size_t)((nn << 7) + c0) << 12) + xb;
        const size_t ob1 = ((size_t)((nn << 7) + c1) << 12) + xb;
        float4 o0, o1;
        o0.x = aw0[0] * iv0; o0.y = aw0[1] * iv1; o0.z = aw0[2] * iv2; o0.w = aw0[3] * iv3;
        o1.x = aw1[0] * iv0; o1.y = aw1[1] * iv1; o1.z = aw1[2] * iv2; o1.w = aw1[3] * iv3;
        *(float4*)&out[ob0] = o0;
        *(float4*)&out[ob1] = o1;
    }
}

extern "C" void kernel_launch(void* const* d_in, const int* in_sizes, int n_in,
                              void* d_out, int out_size, void* d_ws, size_t ws_size,
                              hipStream_t stream) {
    const float* ft = (const float*)d_in[0];
    const float* fk = (const float*)d_in[1];
    const float* Wm = (const float*)d_in[2];
    float* out = (float*)d_out;

    _Float16* Kbuf = (_Float16*)d_ws;                         // [8192][128] fp16
    _Float16* fth  = (_Float16*)d_ws + 1048576;               // [8192][128] fp16
    unsigned int* cnt = (unsigned int*)((char*)d_ws + (4u << 20));

    hipMemsetAsync(cnt, 0, 128, stream);
    ila_merged<<<512, 256, 0, stream>>>(ft, fk, Wm, Kbuf, fth, cnt, out);
}

// Round 9
// 81.230 us; speedup vs baseline: 2.3273x; 1.3135x over previous
//
#include <hip/hip_runtime.h>
#include <hip/hip_bf16.h>

// ILA layer (fp32 I/O): key = W@ft, query = W@fk (1x1 conv, shared W),
// sim[p,k] = <query[p], key[neighbor_k(p)]> over 9x9 window (zero-padded keys),
// weight = softmax_k(sim)  (OOB entries participate with sim=0),
// out[c,p] = sum_k weight[k] * ft[c, neighbor_k(p)]  (zero-padded ft).
// n=2, c=128, h=w=64, L=9 (81 neighbors).
// R27 = revert to R23 two-kernel structure (76.2 us verified; merged-barrier
// line R24-R26 abandoned: fixed harness cost ~57us dominates and the global
// barrier costs ~30us in skew) + kernel A slimmed: W B-fragments loaded
// DIRECTLY from global fp32 (L3-hot) with in-register cvt -> fp16, deleting
// the 64KB W LDS staging pass (43.5KB -> 8.7KB LDS, one less dependency).
// Kernel B byte-identical to R23.

#define Hh 64
#define Ww 64
#define Cc 128
#define Nn 2
#define HW (Hh * Ww)          // 4096
#define CHW (Cc * HW)         // 524288

typedef _Float16 h8 __attribute__((ext_vector_type(8)));
typedef _Float16 h4 __attribute__((ext_vector_type(4)));
typedef float f4v __attribute__((ext_vector_type(4)));

#ifndef __has_builtin
#define __has_builtin(x) 0
#endif

// LDS transpose-read: lane l receives tile[quad*4+j][l&15] of a contiguous
// row-major [16][16] half tile when per-lane addr = tile_base + 8*lane bytes.
#if __has_builtin(__builtin_amdgcn_ds_read_tr16_b64_v4f16)
#define TR_BUILTIN 1
typedef __fp16 g4 __attribute__((__vector_size__(4 * sizeof(__fp16))));
static __device__ __forceinline__ h4 tr16(const _Float16* p) {
    g4 r = __builtin_amdgcn_ds_read_tr16_b64_v4f16(
        (__attribute__((address_space(3))) g4*)p);
    return __builtin_bit_cast(h4, r);
}
#else
#define TR_BUILTIN 0
static __device__ __forceinline__ h4 tr16(const _Float16* p) {
    h4 r;
    asm volatile("ds_read_b64_tr_b16 %0, %1"
                 : "=v"(r)
                 : "v"((__attribute__((address_space(3))) _Float16*)p));
    return r;
}
#endif

// Load 8 consecutive fp32 and convert to an h8 MFMA fragment.
static __device__ __forceinline__ h8 ldW8(const float* __restrict__ p) {
    const float4 v0 = *(const float4*)p;
    const float4 v1 = *(const float4*)(p + 4);
    h8 r;
    r[0] = (_Float16)v0.x; r[1] = (_Float16)v0.y;
    r[2] = (_Float16)v0.z; r[3] = (_Float16)v0.w;
    r[4] = (_Float16)v1.x; r[5] = (_Float16)v1.y;
    r[6] = (_Float16)v1.z; r[7] = (_Float16)v1.w;
    return r;
}

// ---------------- Kernel A: projection via MFMA. 512 blocks x 16 px.
// W fragments read straight from global fp32 (rows nt*16+l15, cols quad*8+32k).
__global__ __launch_bounds__(256) void proj_kernel(const float* __restrict__ ft,
                                                   const float* __restrict__ fk,
                                                   const float* __restrict__ Wm,
                                                   _Float16* __restrict__ Qbuf,
                                                   _Float16* __restrict__ Kbuf,
                                                   _Float16* __restrict__ fth) {
    __shared__ __align__(16) _Float16 xkh[16 * 136];   // [px][c] fp16
    __shared__ __align__(16) _Float16 xqh[16 * 136];
    const int t = threadIdx.x;
    const int p0 = blockIdx.x * 16;       // 4096 % 16 == 0: never crosses n
    const int nn = p0 >> 12;
    const int gbase = nn * CHW + (p0 & 4095);

#pragma unroll
    for (int e = t; e < 512; e += 256) {              // stage x -> fp16 px-major (16 px)
        const int c = e >> 2, pc = e & 3;
        const float4 vk = *(const float4*)&ft[gbase + c * HW + (pc << 2)];
        const float4 vq = *(const float4*)&fk[gbase + c * HW + (pc << 2)];
        const int px = pc << 2;
        xkh[(px    ) * 136 + c] = (_Float16)vk.x;
        xkh[(px + 1) * 136 + c] = (_Float16)vk.y;
        xkh[(px + 2) * 136 + c] = (_Float16)vk.z;
        xkh[(px + 3) * 136 + c] = (_Float16)vk.w;
        xqh[(px    ) * 136 + c] = (_Float16)vq.x;
        xqh[(px + 1) * 136 + c] = (_Float16)vq.y;
        xqh[(px + 2) * 136 + c] = (_Float16)vq.z;
        xqh[(px + 3) * 136 + c] = (_Float16)vq.w;
    }
    __syncthreads();

    {                                                 // fth: coalesced h8 copies (256 e)
        const int px = t >> 4, cq = t & 15;
        *(h8*)&fth[(size_t)(p0 + px) * 128 + (cq << 3)] =
            *(const h8*)&xkh[px * 136 + (cq << 3)];
    }

    const int lane = t & 63, wv = t >> 6;
    const int quad = lane >> 4, l15 = lane & 15;
    const _Float16* xs = (wv >> 1) ? xqh : xkh;
    _Float16* dst = (wv >> 1) ? Qbuf : Kbuf;
    const int nt0 = (wv & 1) << 2;                    // waves split the 8 nt tiles
    const int abase = l15 * 136 + (quad << 3);
    const h8 a0 = *(const h8*)&xs[abase];
    const h8 a1 = *(const h8*)&xs[abase + 32];
    const h8 a2 = *(const h8*)&xs[abase + 64];
    const h8 a3 = *(const h8*)&xs[abase + 96];
#pragma unroll
    for (int ni = 0; ni < 4; ++ni) {
        const int nt = nt0 + ni;
        const float* wrow = &Wm[(nt * 16 + l15) * 128 + (quad << 3)];
        const h8 b0 = ldW8(wrow);
        const h8 b1 = ldW8(wrow + 32);
        const h8 b2 = ldW8(wrow + 64);
        const h8 b3 = ldW8(wrow + 96);
        f4v acc = {0.f, 0.f, 0.f, 0.f};
        acc = __builtin_amdgcn_mfma_f32_16x16x32_f16(a0, b0, acc, 0, 0, 0);
        acc = __builtin_amdgcn_mfma_f32_16x16x32_f16(a1, b1, acc, 0, 0, 0);
        acc = __builtin_amdgcn_mfma_f32_16x16x32_f16(a2, b2, acc, 0, 0, 0);
        acc = __builtin_amdgcn_mfma_f32_16x16x32_f16(a3, b3, acc, 0, 0, 0);
        const int col = nt * 16 + l15;
        const size_t rb = (size_t)(p0 + (quad << 2)) * 128 + col;
#pragma unroll
        for (int r = 0; r < 4; ++r)
            dst[rb + (size_t)r * 128] = (_Float16)acc[r];
    }
}

// ---------------- Kernel B: 16-px (2x8) tile. Window = 10 rows x 16 cols.
// Ksw swizzle: (v<<7) + ((ci ^ (v&15))<<3) halves, v = r*16+xx in [0,160).
// ftl (aliases Ksw after B2): 8 c-chunks x 2568 halves, tile r at chunk*2568+r*256.
#define FTL2 2568
__global__ __launch_bounds__(256, 3) void sim_weight_kernel(const _Float16* __restrict__ Qbuf,
                                                            const _Float16* __restrict__ Kbuf,
                                                            const _Float16* __restrict__ fth,
                                                            float* __restrict__ out) {
    __shared__ __align__(16) unsigned char smem[44192];
    _Float16* Ksw  = (_Float16*)smem;             // [0, 40960)
    _Float16* ftl  = (_Float16*)smem;             // [0, 41088) — written post-B2
    _Float16* simb = (_Float16*)(smem + 41088);   // 81*16 halves [41088, 43680)
    float*    redM = (float*)(smem + 43680);      // 64 floats [wv][p16]
    float*    redS = (float*)(smem + 43936);      // 64 floats [wv][p16]

    const int t  = threadIdx.x;
    const int b  = blockIdx.x;
    const int x0 = (b & 7) << 3;
    const int y0 = ((b >> 3) & 31) << 1;
    const int nn = b >> 8;

    // ---- stage K: zero-padded 10x16 window, h8 copies, XOR-swizzled slots
#pragma unroll
    for (int i = 0; i < 10; ++i) {
        const int e = t + (i << 8);               // 160*16 == 2560 == 10*256
        const int v = e >> 4, ci = e & 15;
        const int gx = x0 + (v & 15) - 4;
        const int gy = y0 + (v >> 4) - 4;
        h8 val = {0, 0, 0, 0, 0, 0, 0, 0};
        if ((unsigned)gx < 64u && (unsigned)gy < 64u)
            val = *(const h8*)&Kbuf[(size_t)((nn << 12) + (gy << 6) + gx) * 128 + (ci << 3)];
        *(h8*)&Ksw[(v << 7) + ((ci ^ (v & 15)) << 3)] = val;
    }
    __syncthreads();   // B1

    // ---- PREFETCH ftl source data into registers: overlaps the whole dot phase
    h8 pf[10];
#pragma unroll
    for (int i = 0; i < 10; ++i) {
        const int e = t + (i << 8);
        const int v = e >> 4, ci = e & 15;
        const int gx = x0 + (v & 15) - 4;
        const int gy = y0 + (v >> 4) - 4;
        h8 val = {0, 0, 0, 0, 0, 0, 0, 0};
        if ((unsigned)gx < 64u && (unsigned)gy < 64u)
            val = *(const h8*)&fth[(size_t)((nn << 12) + (gy << 6) + gx) * 128 + (ci << 3)];
        pf[i] = val;
    }

    // ---- dots via MFMA: per window-row r, S_r[xx][p] = sum_c K[r*16+xx][c]*Q[p][c]
    // Wave wv: rows {wv, wv+4, 8, 9}. p = l15 = 16 real px (py=l15>>3, px=l15&7).
    const int lane = t & 63, wv = t >> 6;
    const int quad = lane >> 4, l15 = lane & 15;
    const int py = l15 >> 3, px = l15 & 7;
    const size_t pgQ = (size_t)((nn << 12) + ((y0 + py) << 6) + x0 + px) * 128;
    f4v sa = {0.f, 0.f, 0.f, 0.f}, sb = sa, sc = sa, sd = sa;
#pragma unroll
    for (int kc = 0; kc < 4; ++kc) {
        const int ci = (kc << 2) + quad;
        const h8 q  = *(const h8*)&Qbuf[pgQ + (ci << 3)];
        const h8 kA = *(const h8*)&Ksw[((((wv    ) << 4) + l15) << 7) + ((ci ^ l15) << 3)];
        const h8 kB = *(const h8*)&Ksw[((((wv + 4) << 4) + l15) << 7) + ((ci ^ l15) << 3)];
        const h8 kC = *(const h8*)&Ksw[((((8     ) << 4) + l15) << 7) + ((ci ^ l15) << 3)];
        const h8 kD = *(const h8*)&Ksw[((((9     ) << 4) + l15) << 7) + ((ci ^ l15) << 3)];
        sa = __builtin_amdgcn_mfma_f32_16x16x32_f16(kA, q, sa, 0, 0, 0);
        sb = __builtin_amdgcn_mfma_f32_16x16x32_f16(kB, q, sb, 0, 0, 0);
        sc = __builtin_amdgcn_mfma_f32_16x16x32_f16(kC, q, sc, 0, 0, 0);
        sd = __builtin_amdgcn_mfma_f32_16x16x32_f16(kD, q, sd, 0, 0, 0);
    }

    // ---- in-layout softmax, phase 1: band-masked max. D: row xx=quad*4+reg, col p=l15.
    // validity: dx = xx-px in [0,9) AND ry = r-py in [0,9).
    float m = -3.0e38f;
#pragma unroll
    for (int reg = 0; reg < 4; ++reg) {
        const int dx = (quad << 2) + reg - px;
        if ((unsigned)dx < 9u) {
            if ((unsigned)(wv - py) < 9u) m = fmaxf(m, sa[reg]);  // r=wv
            m = fmaxf(m, sb[reg]);                                // r=wv+4: ry in [3,8) ok
            m = fmaxf(m, sc[reg]);                                // r=8: ry in {7,8} ok
            if (py) m = fmaxf(m, sd[reg]);                        // r=9: ry=8 only for py=1
        }
    }
    m = fmaxf(m, __shfl_xor(m, 16));
    m = fmaxf(m, __shfl_xor(m, 32));
    if (quad == 0) redM[(wv << 4) + l15] = m;
    __syncthreads();   // B2: dots' Ksw reads done; redM complete; ftl may overwrite

    // ---- restage ft from PREFETCHED registers into [chunk][r][xx][16c] tiles
#pragma unroll
    for (int i = 0; i < 10; ++i) {
        const int e = t + (i << 8);
        const int v = e >> 4, ci = e & 15;
        *(h8*)&ftl[(ci >> 1) * FTL2 + (v << 4) + ((ci & 1) << 3)] = pf[i];
    }

    // ---- phase 2: exp + write simb (fp16, [k81][p16]) + band-masked sum
    const float mm = fmaxf(fmaxf(redM[l15], redM[16 + l15]),
                           fmaxf(redM[32 + l15], redM[48 + l15]));
    float ssum = 0.f;
#pragma unroll
    for (int reg = 0; reg < 4; ++reg) {
        const int dx = (quad << 2) + reg - px;
        const bool okx = (unsigned)dx < 9u;
        {   // r = wv (unique owner)
            const int ry = wv - py;
            const bool ok = okx && ((unsigned)ry < 9u);
            const float e = ok ? __expf(sa[reg] - mm) : 0.f;
            if (ok) simb[((ry * 9 + dx) << 4) + l15] = (_Float16)e;
            ssum += e;
        }
        {   // r = wv+4 (unique owner, ry always valid)
            const int ry = wv + 4 - py;
            const float e = okx ? __expf(sb[reg] - mm) : 0.f;
            if (okx) simb[((ry * 9 + dx) << 4) + l15] = (_Float16)e;
            ssum += e;
        }
        {   // r = 8, owner wave 0
            const int ry = 8 - py;
            const bool ok = okx && (wv == 0);
            const float e = ok ? __expf(sc[reg] - mm) : 0.f;
            if (ok) simb[((ry * 9 + dx) << 4) + l15] = (_Float16)e;
            ssum += e;
        }
        {   // r = 9, owner wave 1, valid only for py=1 (ry=8)
            const bool ok = okx && (wv == 1) && (py == 1);
            const float e = ok ? __expf(sd[reg] - mm) : 0.f;
            if (ok) simb[((8 * 9 + dx) << 4) + l15] = (_Float16)e;
            ssum += e;
        }
    }
    ssum += __shfl_xor(ssum, 16);
    ssum += __shfl_xor(ssum, 32);
    if (quad == 0) redS[(wv << 4) + l15] = ssum;
    __syncthreads();   // B3: ftl + simb + redS complete

    // ---- B-fragments for the weighting MFMAs: 20 tr reads (chunks wv, wv+4)
    const _Float16* ftc0 = ftl + wv * FTL2;
    const _Float16* ftc1 = ftl + (wv + 4) * FTL2;
    h4 bfr[20];
#pragma unroll
    for (int r = 0; r < 10; ++r) {
        bfr[r]      = tr16(ftc0 + (r << 8) + (lane << 2));
        bfr[10 + r] = tr16(ftc1 + (r << 8) + (lane << 2));
    }

#if !TR_BUILTIN
    asm volatile("s_waitcnt lgkmcnt(0)");   // rule-#18 fence for asm-path bfr
    __builtin_amdgcn_sched_barrier(0);
#endif

    // ---- weighting via MFMA: per window-row r, D[p][c] += A[p][xx] * B_r[xx][c]
    // A[p][xx] = simb[(r-py)*9 + (xx-px)][p] on the band; A-frag row = l15 = p.
    f4v aw0 = {0.f, 0.f, 0.f, 0.f}, aw1 = aw0;
#pragma unroll
    for (int r = 0; r < 10; ++r) {
        const int ry = r - py;
        const bool okr = (unsigned)ry < 9u;
        h4 afr;
#pragma unroll
        for (int j = 0; j < 4; ++j) {
            const int dx = (quad << 2) + j - px;
            const bool ok = okr && ((unsigned)dx < 9u);
            afr[j] = ok ? simb[(((ry * 9 + dx) << 4)) + l15] : (_Float16)0.f;
        }
        aw0 = __builtin_amdgcn_mfma_f32_16x16x16f16(afr, bfr[r],      aw0, 0, 0, 0);
        aw1 = __builtin_amdgcn_mfma_f32_16x16x16f16(afr, bfr[10 + r], aw1, 0, 0, 0);
    }

    // D layout: row = p = quad*4+reg (16 real px), col = c-in-chunk = l15.
    // quad -> (row py0 = quad>>1, x-segment (quad&1)*4): 4 consecutive x per lane.
    {
        const int p0q = quad << 2;
        const float iv0 = 1.f / (redS[p0q    ] + redS[16 + p0q    ] + redS[32 + p0q    ] + redS[48 + p0q    ]);
        const float iv1 = 1.f / (redS[p0q + 1] + redS[16 + p0q + 1] + redS[32 + p0q + 1] + redS[48 + p0q + 1]);
        const float iv2 = 1.f / (redS[p0q + 2] + redS[16 + p0q + 2] + redS[32 + p0q + 2] + redS[48 + p0q + 2]);
        const float iv3 = 1.f / (redS[p0q + 3] + redS[16 + p0q + 3] + redS[32 + p0q + 3] + redS[48 + p0q + 3]);
        const int yo = y0 + (p0q >> 3);
        const int xb = (yo << 6) + x0 + (p0q & 7);
        const int c0 = (wv << 4) + l15;
        const int c1 = ((wv + 4) << 4) + l15;
        const size_t ob0 = ((size_t)((nn << 7) + c0) << 12) + xb;
        const size_t ob1 = ((size_t)((nn << 7) + c1) << 12) + xb;
        float4 o0, o1;
        o0.x = aw0[0] * iv0; o0.y = aw0[1] * iv1; o0.z = aw0[2] * iv2; o0.w = aw0[3] * iv3;
        o1.x = aw1[0] * iv0; o1.y = aw1[1] * iv1; o1.z = aw1[2] * iv2; o1.w = aw1[3] * iv3;
        *(float4*)&out[ob0] = o0;
        *(float4*)&out[ob1] = o1;
    }
}

extern "C" void kernel_launch(void* const* d_in, const int* in_sizes, int n_in,
                              void* d_out, int out_size, void* d_ws, size_t ws_size,
                              hipStream_t stream) {
    const float* ft = (const float*)d_in[0];
    const float* fk = (const float*)d_in[1];
    const float* Wm = (const float*)d_in[2];
    float* out = (float*)d_out;

    _Float16* wsh  = (_Float16*)d_ws;    // 6 MB: Qh(2MB) + Kh(2MB) + fth(2MB)
    _Float16* Qbuf = wsh;                // [p][c]  8192*128 halves
    _Float16* Kbuf = wsh + 1048576;      // [p][c]  8192*128 halves
    _Float16* fth  = wsh + 2097152;      // fp16 ft, PIXEL-MAJOR [p][c]

    proj_kernel<<<512, 256, 0, stream>>>(ft, fk, Wm, Qbuf, Kbuf, fth);
    sim_weight_kernel<<<512, 256, 0, stream>>>(Qbuf, Kbuf, fth, out);
}

// Round 10
// 77.665 us; speedup vs baseline: 2.4341x; 1.0459x over previous
//
#include <hip/hip_runtime.h>
#include <hip/hip_bf16.h>

// ILA layer (fp32 I/O): key = W@ft, query = W@fk (1x1 conv, shared W),
// sim[p,k] = <query[p], key[neighbor_k(p)]> over 9x9 window (zero-padded keys),
// weight = softmax_k(sim)  (OOB entries participate with sim=0),
// out[c,p] = sum_k weight[k] * ft[c, neighbor_k(p)]  (zero-padded ft).
// n=2, c=128, h=w=64, L=9 (81 neighbors).
// R28 = EXACT RESTORE of R23 (76.2 us measured-best).
// Nine-round record: R22 full-fusion +7.5us; R24-R26 cooperative-merge
// +30..+110us (global-barrier skew + cache-maintenance); R27 W-direct +5us
// (uncoalesced W reads + global latency ahead of MFMA). All reverted.
// Structure: kernel A projects 16 px/block (512 blocks, W via LDS);
// kernel B 2x8-px output tile, 10x16 window, MFMA dots + in-layout softmax +
// tr16 MFMA weighting, 3 barriers.

#define Hh 64
#define Ww 64
#define Cc 128
#define Nn 2
#define HW (Hh * Ww)          // 4096
#define CHW (Cc * HW)         // 524288

typedef _Float16 h8 __attribute__((ext_vector_type(8)));
typedef _Float16 h4 __attribute__((ext_vector_type(4)));
typedef float f4v __attribute__((ext_vector_type(4)));

#ifndef __has_builtin
#define __has_builtin(x) 0
#endif

// LDS transpose-read: lane l receives tile[quad*4+j][l&15] of a contiguous
// row-major [16][16] half tile when per-lane addr = tile_base + 8*lane bytes.
#if __has_builtin(__builtin_amdgcn_ds_read_tr16_b64_v4f16)
#define TR_BUILTIN 1
typedef __fp16 g4 __attribute__((__vector_size__(4 * sizeof(__fp16))));
static __device__ __forceinline__ h4 tr16(const _Float16* p) {
    g4 r = __builtin_amdgcn_ds_read_tr16_b64_v4f16(
        (__attribute__((address_space(3))) g4*)p);
    return __builtin_bit_cast(h4, r);
}
#else
#define TR_BUILTIN 0
static __device__ __forceinline__ h4 tr16(const _Float16* p) {
    h4 r;
    asm volatile("ds_read_b64_tr_b16 %0, %1"
                 : "=v"(r)
                 : "v"((__attribute__((address_space(3))) _Float16*)p));
    return r;
}
#endif

// ---------------- Kernel A: projection via MFMA. 512 blocks x 16 px.
__global__ __launch_bounds__(256) void proj_kernel(const float* __restrict__ ft,
                                                   const float* __restrict__ fk,
                                                   const float* __restrict__ Wm,
                                                   _Float16* __restrict__ Qbuf,
                                                   _Float16* __restrict__ Kbuf,
                                                   _Float16* __restrict__ fth) {
    __shared__ __align__(16) _Float16 Wth[128 * 136];  // [o][i] fp16 (== B[k][n] view)
    __shared__ __align__(16) _Float16 xkh[16 * 136];   // [px][c] fp16
    __shared__ __align__(16) _Float16 xqh[16 * 136];
    const int t = threadIdx.x;
    const int p0 = blockIdx.x * 16;       // 4096 % 16 == 0: never crosses n
    const int nn = p0 >> 12;
    const int gbase = nn * CHW + (p0 & 4095);

#pragma unroll 4
    for (int e = t; e < 4096; e += 256) {             // stage W -> fp16
        const int n = e >> 5, ch = e & 31;
        const float4 v = *(const float4*)&Wm[n * 128 + (ch << 2)];
        h4 hv; hv[0] = (_Float16)v.x; hv[1] = (_Float16)v.y;
               hv[2] = (_Float16)v.z; hv[3] = (_Float16)v.w;
        *(h4*)&Wth[n * 136 + (ch << 2)] = hv;
    }
#pragma unroll
    for (int e = t; e < 512; e += 256) {              // stage x -> fp16 px-major (16 px)
        const int c = e >> 2, pc = e & 3;
        const float4 vk = *(const float4*)&ft[gbase + c * HW + (pc << 2)];
        const float4 vq = *(const float4*)&fk[gbase + c * HW + (pc << 2)];
        const int px = pc << 2;
        xkh[(px    ) * 136 + c] = (_Float16)vk.x;
        xkh[(px + 1) * 136 + c] = (_Float16)vk.y;
        xkh[(px + 2) * 136 + c] = (_Float16)vk.z;
        xkh[(px + 3) * 136 + c] = (_Float16)vk.w;
        xqh[(px    ) * 136 + c] = (_Float16)vq.x;
        xqh[(px + 1) * 136 + c] = (_Float16)vq.y;
        xqh[(px + 2) * 136 + c] = (_Float16)vq.z;
        xqh[(px + 3) * 136 + c] = (_Float16)vq.w;
    }
    __syncthreads();

    {                                                 // fth: coalesced h8 copies (256 e)
        const int px = t >> 4, cq = t & 15;
        *(h8*)&fth[(size_t)(p0 + px) * 128 + (cq << 3)] =
            *(const h8*)&xkh[px * 136 + (cq << 3)];
    }

    const int lane = t & 63, wv = t >> 6;
    const int quad = lane >> 4, l15 = lane & 15;
    const _Float16* xs = (wv >> 1) ? xqh : xkh;
    _Float16* dst = (wv >> 1) ? Qbuf : Kbuf;
    const int nt0 = (wv & 1) << 2;                    // waves split the 8 nt tiles
    const int abase = l15 * 136 + (quad << 3);
    const h8 a0 = *(const h8*)&xs[abase];
    const h8 a1 = *(const h8*)&xs[abase + 32];
    const h8 a2 = *(const h8*)&xs[abase + 64];
    const h8 a3 = *(const h8*)&xs[abase + 96];
#pragma unroll
    for (int ni = 0; ni < 4; ++ni) {
        const int nt = nt0 + ni;
        const int bbase = (nt * 16 + l15) * 136 + (quad << 3);
        const h8 b0 = *(const h8*)&Wth[bbase];
        const h8 b1 = *(const h8*)&Wth[bbase + 32];
        const h8 b2 = *(const h8*)&Wth[bbase + 64];
        const h8 b3 = *(const h8*)&Wth[bbase + 96];
        f4v acc = {0.f, 0.f, 0.f, 0.f};
        acc = __builtin_amdgcn_mfma_f32_16x16x32_f16(a0, b0, acc, 0, 0, 0);
        acc = __builtin_amdgcn_mfma_f32_16x16x32_f16(a1, b1, acc, 0, 0, 0);
        acc = __builtin_amdgcn_mfma_f32_16x16x32_f16(a2, b2, acc, 0, 0, 0);
        acc = __builtin_amdgcn_mfma_f32_16x16x32_f16(a3, b3, acc, 0, 0, 0);
        const int col = nt * 16 + l15;
        const size_t rb = (size_t)(p0 + (quad << 2)) * 128 + col;
#pragma unroll
        for (int r = 0; r < 4; ++r)
            dst[rb + (size_t)r * 128] = (_Float16)acc[r];
    }
}

// ---------------- Kernel B: 16-px (2x8) tile. Window = 10 rows x 16 cols.
// Ksw swizzle: (v<<7) + ((ci ^ (v&15))<<3) halves, v = r*16+xx in [0,160).
// ftl (aliases Ksw after B2): 8 c-chunks x 2568 halves, tile r at chunk*2568+r*256.
#define FTL2 2568
__global__ __launch_bounds__(256, 3) void sim_weight_kernel(const _Float16* __restrict__ Qbuf,
                                                            const _Float16* __restrict__ Kbuf,
                                                            const _Float16* __restrict__ fth,
                                                            float* __restrict__ out) {
    __shared__ __align__(16) unsigned char smem[44192];
    _Float16* Ksw  = (_Float16*)smem;             // [0, 40960)
    _Float16* ftl  = (_Float16*)smem;             // [0, 41088) — written post-B2
    _Float16* simb = (_Float16*)(smem + 41088);   // 81*16 halves [41088, 43680)
    float*    redM = (float*)(smem + 43680);      // 64 floats [wv][p16]
    float*    redS = (float*)(smem + 43936);      // 64 floats [wv][p16]

    const int t  = threadIdx.x;
    const int b  = blockIdx.x;
    const int x0 = (b & 7) << 3;
    const int y0 = ((b >> 3) & 31) << 1;
    const int nn = b >> 8;

    // ---- stage K: zero-padded 10x16 window, h8 copies, XOR-swizzled slots
#pragma unroll
    for (int i = 0; i < 10; ++i) {
        const int e = t + (i << 8);               // 160*16 == 2560 == 10*256
        const int v = e >> 4, ci = e & 15;
        const int gx = x0 + (v & 15) - 4;
        const int gy = y0 + (v >> 4) - 4;
        h8 val = {0, 0, 0, 0, 0, 0, 0, 0};
        if ((unsigned)gx < 64u && (unsigned)gy < 64u)
            val = *(const h8*)&Kbuf[(size_t)((nn << 12) + (gy << 6) + gx) * 128 + (ci << 3)];
        *(h8*)&Ksw[(v << 7) + ((ci ^ (v & 15)) << 3)] = val;
    }
    __syncthreads();   // B1

    // ---- PREFETCH ftl source data into registers: overlaps the whole dot phase
    h8 pf[10];
#pragma unroll
    for (int i = 0; i < 10; ++i) {
        const int e = t + (i << 8);
        const int v = e >> 4, ci = e & 15;
        const int gx = x0 + (v & 15) - 4;
        const int gy = y0 + (v >> 4) - 4;
        h8 val = {0, 0, 0, 0, 0, 0, 0, 0};
        if ((unsigned)gx < 64u && (unsigned)gy < 64u)
            val = *(const h8*)&fth[(size_t)((nn << 12) + (gy << 6) + gx) * 128 + (ci << 3)];
        pf[i] = val;
    }

    // ---- dots via MFMA: per window-row r, S_r[xx][p] = sum_c K[r*16+xx][c]*Q[p][c]
    // Wave wv: rows {wv, wv+4, 8, 9}. p = l15 = 16 real px (py=l15>>3, px=l15&7).
    const int lane = t & 63, wv = t >> 6;
    const int quad = lane >> 4, l15 = lane & 15;
    const int py = l15 >> 3, px = l15 & 7;
    const size_t pgQ = (size_t)((nn << 12) + ((y0 + py) << 6) + x0 + px) * 128;
    f4v sa = {0.f, 0.f, 0.f, 0.f}, sb = sa, sc = sa, sd = sa;
#pragma unroll
    for (int kc = 0; kc < 4; ++kc) {
        const int ci = (kc << 2) + quad;
        const h8 q  = *(const h8*)&Qbuf[pgQ + (ci << 3)];
        const h8 kA = *(const h8*)&Ksw[((((wv    ) << 4) + l15) << 7) + ((ci ^ l15) << 3)];
        const h8 kB = *(const h8*)&Ksw[((((wv + 4) << 4) + l15) << 7) + ((ci ^ l15) << 3)];
        const h8 kC = *(const h8*)&Ksw[((((8     ) << 4) + l15) << 7) + ((ci ^ l15) << 3)];
        const h8 kD = *(const h8*)&Ksw[((((9     ) << 4) + l15) << 7) + ((ci ^ l15) << 3)];
        sa = __builtin_amdgcn_mfma_f32_16x16x32_f16(kA, q, sa, 0, 0, 0);
        sb = __builtin_amdgcn_mfma_f32_16x16x32_f16(kB, q, sb, 0, 0, 0);
        sc = __builtin_amdgcn_mfma_f32_16x16x32_f16(kC, q, sc, 0, 0, 0);
        sd = __builtin_amdgcn_mfma_f32_16x16x32_f16(kD, q, sd, 0, 0, 0);
    }

    // ---- in-layout softmax, phase 1: band-masked max. D: row xx=quad*4+reg, col p=l15.
    // validity: dx = xx-px in [0,9) AND ry = r-py in [0,9).
    float m = -3.0e38f;
#pragma unroll
    for (int reg = 0; reg < 4; ++reg) {
        const int dx = (quad << 2) + reg - px;
        if ((unsigned)dx < 9u) {
            if ((unsigned)(wv - py) < 9u) m = fmaxf(m, sa[reg]);  // r=wv
            m = fmaxf(m, sb[reg]);                                // r=wv+4: ry in [3,8) ok
            m = fmaxf(m, sc[reg]);                                // r=8: ry in {7,8} ok
            if (py) m = fmaxf(m, sd[reg]);                        // r=9: ry=8 only for py=1
        }
    }
    m = fmaxf(m, __shfl_xor(m, 16));
    m = fmaxf(m, __shfl_xor(m, 32));
    if (quad == 0) redM[(wv << 4) + l15] = m;
    __syncthreads();   // B2: dots' Ksw reads done; redM complete; ftl may overwrite

    // ---- restage ft from PREFETCHED registers into [chunk][r][xx][16c] tiles
#pragma unroll
    for (int i = 0; i < 10; ++i) {
        const int e = t + (i << 8);
        const int v = e >> 4, ci = e & 15;
        *(h8*)&ftl[(ci >> 1) * FTL2 + (v << 4) + ((ci & 1) << 3)] = pf[i];
    }

    // ---- phase 2: exp + write simb (fp16, [k81][p16]) + band-masked sum
    const float mm = fmaxf(fmaxf(redM[l15], redM[16 + l15]),
                           fmaxf(redM[32 + l15], redM[48 + l15]));
    float ssum = 0.f;
#pragma unroll
    for (int reg = 0; reg < 4; ++reg) {
        const int dx = (quad << 2) + reg - px;
        const bool okx = (unsigned)dx < 9u;
        {   // r = wv (unique owner)
            const int ry = wv - py;
            const bool ok = okx && ((unsigned)ry < 9u);
            const float e = ok ? __expf(sa[reg] - mm) : 0.f;
            if (ok) simb[((ry * 9 + dx) << 4) + l15] = (_Float16)e;
            ssum += e;
        }
        {   // r = wv+4 (unique owner, ry always valid)
            const int ry = wv + 4 - py;
            const float e = okx ? __expf(sb[reg] - mm) : 0.f;
            if (okx) simb[((ry * 9 + dx) << 4) + l15] = (_Float16)e;
            ssum += e;
        }
        {   // r = 8, owner wave 0
            const int ry = 8 - py;
            const bool ok = okx && (wv == 0);
            const float e = ok ? __expf(sc[reg] - mm) : 0.f;
            if (ok) simb[((ry * 9 + dx) << 4) + l15] = (_Float16)e;
            ssum += e;
        }
        {   // r = 9, owner wave 1, valid only for py=1 (ry=8)
            const bool ok = okx && (wv == 1) && (py == 1);
            const float e = ok ? __expf(sd[reg] - mm) : 0.f;
            if (ok) simb[((8 * 9 + dx) << 4) + l15] = (_Float16)e;
            ssum += e;
        }
    }
    ssum += __shfl_xor(ssum, 16);
    ssum += __shfl_xor(ssum, 32);
    if (quad == 0) redS[(wv << 4) + l15] = ssum;
    __syncthreads();   // B3: ftl + simb + redS complete

    // ---- B-fragments for the weighting MFMAs: 20 tr reads (chunks wv, wv+4)
    const _Float16* ftc0 = ftl + wv * FTL2;
    const _Float16* ftc1 = ftl + (wv + 4) * FTL2;
    h4 bfr[20];
#pragma unroll
    for (int r = 0; r < 10; ++r) {
        bfr[r]      = tr16(ftc0 + (r << 8) + (lane << 2));
        bfr[10 + r] = tr16(ftc1 + (r << 8) + (lane << 2));
    }

#if !TR_BUILTIN
    asm volatile("s_waitcnt lgkmcnt(0)");   // rule-#18 fence for asm-path bfr
    __builtin_amdgcn_sched_barrier(0);
#endif

    // ---- weighting via MFMA: per window-row r, D[p][c] += A[p][xx] * B_r[xx][c]
    // A[p][xx] = simb[(r-py)*9 + (xx-px)][p] on the band; A-frag row = l15 = p.
    f4v aw0 = {0.f, 0.f, 0.f, 0.f}, aw1 = aw0;
#pragma unroll
    for (int r = 0; r < 10; ++r) {
        const int ry = r - py;
        const bool okr = (unsigned)ry < 9u;
        h4 afr;
#pragma unroll
        for (int j = 0; j < 4; ++j) {
            const int dx = (quad << 2) + j - px;
            const bool ok = okr && ((unsigned)dx < 9u);
            afr[j] = ok ? simb[(((ry * 9 + dx) << 4)) + l15] : (_Float16)0.f;
        }
        aw0 = __builtin_amdgcn_mfma_f32_16x16x16f16(afr, bfr[r],      aw0, 0, 0, 0);
        aw1 = __builtin_amdgcn_mfma_f32_16x16x16f16(afr, bfr[10 + r], aw1, 0, 0, 0);
    }

    // D layout: row = p = quad*4+reg (16 real px), col = c-in-chunk = l15.
    // quad -> (row py0 = quad>>1, x-segment (quad&1)*4): 4 consecutive x per lane.
    {
        const int p0q = quad << 2;
        const float iv0 = 1.f / (redS[p0q    ] + redS[16 + p0q    ] + redS[32 + p0q    ] + redS[48 + p0q    ]);
        const float iv1 = 1.f / (redS[p0q + 1] + redS[16 + p0q + 1] + redS[32 + p0q + 1] + redS[48 + p0q + 1]);
        const float iv2 = 1.f / (redS[p0q + 2] + redS[16 + p0q + 2] + redS[32 + p0q + 2] + redS[48 + p0q + 2]);
        const float iv3 = 1.f / (redS[p0q + 3] + redS[16 + p0q + 3] + redS[32 + p0q + 3] + redS[48 + p0q + 3]);
        const int yo = y0 + (p0q >> 3);
        const int xb = (yo << 6) + x0 + (p0q & 7);
        const int c0 = (wv << 4) + l15;
        const int c1 = ((wv + 4) << 4) + l15;
        const size_t ob0 = ((size_t)((nn << 7) + c0) << 12) + xb;
        const size_t ob1 = ((size_t)((nn << 7) + c1) << 12) + xb;
        float4 o0, o1;
        o0.x = aw0[0] * iv0; o0.y = aw0[1] * iv1; o0.z = aw0[2] * iv2; o0.w = aw0[3] * iv3;
        o1.x = aw1[0] * iv0; o1.y = aw1[1] * iv1; o1.z = aw1[2] * iv2; o1.w = aw1[3] * iv3;
        *(float4*)&out[ob0] = o0;
        *(float4*)&out[ob1] = o1;
    }
}

extern "C" void kernel_launch(void* const* d_in, const int* in_sizes, int n_in,
                              void* d_out, int out_size, void* d_ws, size_t ws_size,
                              hipStream_t stream) {
    const float* ft = (const float*)d_in[0];
    const float* fk = (const float*)d_in[1];
    const float* Wm = (const float*)d_in[2];
    float* out = (float*)d_out;

    _Float16* wsh  = (_Float16*)d_ws;    // 6 MB: Qh(2MB) + Kh(2MB) + fth(2MB)
    _Float16* Qbuf = wsh;                // [p][c]  8192*128 halves
    _Float16* Kbuf = wsh + 1048576;      // [p][c]  8192*128 halves
    _Float16* fth  = wsh + 2097152;      // fp16 ft, PIXEL-MAJOR [p][c]

    proj_kernel<<<512, 256, 0, stream>>>(ft, fk, Wm, Qbuf, Kbuf, fth);
    sim_weight_kernel<<<512, 256, 0, stream>>>(Qbuf, Kbuf, fth, out);
}